// Round 6
// baseline (3616.726 us; speedup 1.0000x reference)
//
#include <hip/hip_runtime.h>
#include <hip/hip_fp16.h>
#include <cstdint>
#include <cstddef>

#define B_ 128
#define T_ 2048
#define C_ 16
#define CO_ 128
#define H_ 128
#define G_ 512
#define WCV 120                 // conv/x0 worker blocks
#define WZ1 120                 // z1 (Wih1.h0) worker blocks
#define NBLK (16 + WCV + WZ1)   // 256
#define L2E  1.4426950408889634f
#define L2E2 2.8853900817779268f

typedef _Float16 half8 __attribute__((ext_vector_type(8)));
typedef float f32x4 __attribute__((ext_vector_type(4)));

__device__ __forceinline__ unsigned packh2f(float a, float b) {
  union { _Float16 h[2]; unsigned u; } x;
  x.h[0] = (_Float16)a; x.h[1] = (_Float16)b;
  return x.u;
}

__device__ __forceinline__ float rcpf(float x) { return __builtin_amdgcn_rcpf(x); }

__device__ __forceinline__ float exp2f_(float x) {
#if __has_builtin(__builtin_amdgcn_exp2f)
  return __builtin_amdgcn_exp2f(x);
#else
  return __expf(x * 0.6931471805599453f);
#endif
}

// Gates arrive PRE-SCALED: i,f,o by log2e; g by 2*log2e.
__device__ __forceinline__ void lstm_cell(const f32x4* acc, f32x4& c, float* h) {
#pragma unroll
  for (int r = 0; r < 4; ++r) {
    float iv = acc[0][r], fv = acc[1][r], gv = acc[2][r], ov = acc[3][r];
    gv = fminf(fmaxf(gv, -43.3f), 43.3f);
    float ei = exp2f_(-iv), ef = exp2f_(-fv), eg = exp2f_(gv);
    float P = (1.f + ei) * (eg + 1.f);   // sig(i)*tanh(g) = (eg-1)/P
    float Q = 1.f + ef;                  // sig(f) = 1/Q
    float num = c[r] * P + (eg - 1.f) * Q;
    float cN = num * rcpf(Q * P);
    c[r] = cN;
    float cc = fminf(fmaxf(cN, -15.f), 15.f);
    float eo = exp2f_(-ov), ec = exp2f_(L2E2 * cc);
    h[r] = (ec - 1.f) * rcpf((1.f + eo) * (ec + 1.f));
  }
}

// ---------------------------------------------------------------------------
// pack_kernel: fragment-ordered weight buffers, rows pre-scaled by log2e /
// 2*log2e (g gate) so the cell can use raw exp2.
// ---------------------------------------------------------------------------
__global__ __launch_bounds__(256) void pack_kernel(
    const float* __restrict__ w_ih0, const float* __restrict__ w_hh0,
    const float* __restrict__ w_ih1, const float* __restrict__ w_hh1,
    const float* __restrict__ b_ih1, const float* __restrict__ b_hh1,
    uint4* __restrict__ Wf0, uint4* __restrict__ Wih1f,
    uint4* __restrict__ Whh1f, uint4* __restrict__ WB0f,
    f32x4* __restrict__ b1fD) {
  int tid = blockIdx.x * 256 + threadIdx.x;
  if (tid < 24576) {
    int u = tid & 8191, L = u & 63, s = (u >> 6) & 3, tl = (u >> 8) & 3, w = u >> 10;
    int which = tid >> 13;
    const float* src = (which == 0) ? w_hh0 : (which == 1) ? w_ih1 : w_hh1;
    uint4* dst = (which == 0) ? Wf0 : (which == 1) ? Wih1f : Whh1f;
    int m = (w + 8 * tl) * 16 + (L & 15);     // gate index == tl (m>>7)
    float sc = (tl == 2) ? L2E2 : L2E;
    int k0 = s * 32 + (L >> 4) * 8;
    const float* p = src + m * 128 + k0;
    uint4 o;
    o.x = packh2f(p[0] * sc, p[1] * sc); o.y = packh2f(p[2] * sc, p[3] * sc);
    o.z = packh2f(p[4] * sc, p[5] * sc); o.w = packh2f(p[6] * sc, p[7] * sc);
    dst[u] = o;
  } else if (tid < 32768) {
    int u = tid - 24576, L = u & 63, s = (u >> 6) & 3, nt = u >> 8;
    int g = nt * 16 + (L & 15);
    float sc = ((nt >> 3) == 2) ? L2E2 : L2E;
    int k0 = s * 32 + (L >> 4) * 8;
    const float* p = w_ih0 + g * 128 + k0;
    uint4 o;
    o.x = packh2f(p[0] * sc, p[1] * sc); o.y = packh2f(p[2] * sc, p[3] * sc);
    o.z = packh2f(p[4] * sc, p[5] * sc); o.w = packh2f(p[6] * sc, p[7] * sc);
    WB0f[u] = o;
  } else if (tid < 34816) {
    int u2 = tid - 32768;
    int tl = u2 & 3, L = (u2 >> 2) & 63, w = u2 >> 8;
    int q = L >> 4;
    float sc = (tl == 2) ? L2E2 : L2E;
    f32x4 o;
#pragma unroll
    for (int reg = 0; reg < 4; ++reg) {
      int row = (w + 8 * tl) * 16 + q * 4 + reg;
      o[reg] = (b_ih1[row] + b_hh1[row]) * sc;
    }
    b1fD[u2] = o;
  }
}

// ---------------------------------------------------------------------------
// persist_kernel:
//  blocks 0..7    : layer-0 recurrence (batch group b16 = bid)
//  blocks 8..15   : layer-1 recurrence (only Whh1 MFMA; z1 precomputed)
//  blocks 16..135 : conv+x0 producers (x0 ring, 32-step tiles)
//  blocks 136..255: z1 producers (z1 = Wih1.h0 + b1, 8-step units, z1 ring)
// Flags: xready[64*8], l0_prog[8], l1_prog[8], z1r[256*8].
// ---------------------------------------------------------------------------
__global__ __launch_bounds__(512, 2) void persist_kernel(
    const float* __restrict__ x, const float* __restrict__ conv_w,
    const float* __restrict__ conv_b, const float* __restrict__ b_ih0,
    const float* __restrict__ b_hh0,
    const uint4* __restrict__ Wf0, const uint4* __restrict__ Wih1f,
    const uint4* __restrict__ Whh1f, const uint4* __restrict__ WB0f,
    const f32x4* __restrict__ b1fD,
    uint4* __restrict__ x0f, uint2* __restrict__ h0g, uint4* __restrict__ z1f,
    f32x4* __restrict__ psave,
    int* __restrict__ xready, int* __restrict__ l0_prog,
    int* __restrict__ l1_prog, int* __restrict__ z1r,
    int rmask, int rmask2) {
  __shared__ __align__(16) union {
    struct { float xs[34 * 16]; _Float16 yh[32 * 136]; _Float16 x0S[32 * 512]; } wk;
    struct { _Float16 h[2][16 * 136]; } rc;
  } sm;

  const int bid = blockIdx.x;
  const int tid = threadIdx.x;
  const int w = tid >> 6, L = tid & 63, q = L >> 4, n = L & 15;

  if (bid < 8) {
    // ---------------- layer-0 recurrence ----------------
    const int b16 = bid;
    half8 WA0[4][4];
#pragma unroll
    for (int tl = 0; tl < 4; ++tl)
#pragma unroll
      for (int s = 0; s < 4; ++s)
        WA0[tl][s] = __builtin_bit_cast(half8, Wf0[((w * 4 + tl) * 4 + s) * 64 + L]);

    f32x4 c0v = {0.f, 0.f, 0.f, 0.f};
    const int hoff = n * 136 + w * 16 + q * 4;
    *(uint2*)&sm.rc.h[1][hoff] = make_uint2(0u, 0u);
    __syncthreads();

    const uint4* xp = x0f + (((size_t)b16 * 8 + w) * 64 + L) * 2;
    uint2* hg = h0g + ((b16 * 16 + n) * 32 + w * 4 + q);
    uint4 pa[4], pb[4];

    for (int g = 0; g < 64; ++g) {
      if (tid == 0) {
        while (__hip_atomic_load(&xready[g * 8 + b16], __ATOMIC_ACQUIRE,
                                 __HIP_MEMORY_SCOPE_AGENT) < 16)
          __builtin_amdgcn_s_sleep(2);
        if (g < 63)
          while (__hip_atomic_load(&xready[(g + 1) * 8 + b16], __ATOMIC_ACQUIRE,
                                   __HIP_MEMORY_SCOPE_AGENT) < 16)
            __builtin_amdgcn_s_sleep(2);
      }
      __syncthreads();
      if (g == 0) {
#pragma unroll
        for (int k = 0; k < 4; ++k) {
          pa[k] = xp[(size_t)k * 8192];
          pb[k] = xp[(size_t)k * 8192 + 1];
        }
      }
#pragma unroll 1
      for (int io = 0; io < 8; ++io) {
#pragma unroll
        for (int k = 0; k < 4; ++k) {
          const int t = g * 32 + io * 4 + k;
          const int c = k & 1, p = c ^ 1;
          f32x4 acc[4];
          {
            half8 xlo = __builtin_bit_cast(half8, pa[k]);
            half8 xhi = __builtin_bit_cast(half8, pb[k]);
            acc[0] = (f32x4){(float)xlo[0], (float)xlo[1], (float)xlo[2], (float)xlo[3]};
            acc[1] = (f32x4){(float)xlo[4], (float)xlo[5], (float)xlo[6], (float)xlo[7]};
            acc[2] = (f32x4){(float)xhi[0], (float)xhi[1], (float)xhi[2], (float)xhi[3]};
            acc[3] = (f32x4){(float)xhi[4], (float)xhi[5], (float)xhi[6], (float)xhi[7]};
          }
          half8 B0[4];
#pragma unroll
          for (int s = 0; s < 4; ++s)
            B0[s] = *(const half8*)&sm.rc.h[p][n * 136 + s * 32 + q * 8];
#pragma unroll
          for (int s = 0; s < 4; ++s)
#pragma unroll
            for (int tl = 0; tl < 4; ++tl)
              acc[tl] = __builtin_amdgcn_mfma_f32_16x16x32_f16(WA0[tl][s], B0[s], acc[tl], 0, 0, 0);

          float h0v[4];
          lstm_cell(acc, c0v, h0v);
          uint2 h0p;
          h0p.x = packh2f(h0v[0], h0v[1]);
          h0p.y = packh2f(h0v[2], h0v[3]);
          *(uint2*)&sm.rc.h[c][hoff] = h0p;
          hg[(size_t)t * 4096] = h0p;

          const bool dopub = (io & 1) && (k == 3);
          if (dopub) asm volatile("s_waitcnt vmcnt(0)" ::: "memory");
          __syncthreads();
          if (dopub && tid == 0)
            __hip_atomic_store(&l0_prog[b16], t + 1, __ATOMIC_RELEASE,
                               __HIP_MEMORY_SCOPE_AGENT);
          int tn = t + 4; if (tn > T_ - 1) tn = T_ - 1;
          const size_t so = (size_t)(tn & rmask) * 8192;
          pa[k] = xp[so];
          pb[k] = xp[so + 1];
        }
      }
    }
  } else if (bid < 16) {
    // ---------------- layer-1 recurrence (z1 precomputed by workers) --------
    const int b16 = bid - 8;
    half8 WH[4][4];
#pragma unroll
    for (int tl = 0; tl < 4; ++tl)
#pragma unroll
      for (int s = 0; s < 4; ++s)
        WH[tl][s] = __builtin_bit_cast(half8, Whh1f[((w * 4 + tl) * 4 + s) * 64 + L]);

    f32x4 c1v = {0.f, 0.f, 0.f, 0.f};
    f32x4 pool = {0.f, 0.f, 0.f, 0.f};
    const int hoff = n * 136 + w * 16 + q * 4;
    *(uint2*)&sm.rc.h[1][hoff] = make_uint2(0u, 0u);
    __syncthreads();

    const uint4* zp = z1f + (((size_t)b16 * 8 + w) * 64 + L) * 2;
    uint4 pa[4], pb[4];

    for (int g8 = 0; g8 < 256; ++g8) {
      if (tid == 0) {
        while (__hip_atomic_load(&z1r[g8 * 8 + b16], __ATOMIC_ACQUIRE,
                                 __HIP_MEMORY_SCOPE_AGENT) < 1)
          __builtin_amdgcn_s_sleep(2);
        if (g8 < 255)
          while (__hip_atomic_load(&z1r[(g8 + 1) * 8 + b16], __ATOMIC_ACQUIRE,
                                   __HIP_MEMORY_SCOPE_AGENT) < 1)
            __builtin_amdgcn_s_sleep(2);
      }
      __syncthreads();
      if (g8 == 0) {
#pragma unroll
        for (int k = 0; k < 4; ++k) {
          pa[k] = zp[(size_t)k * 8192];
          pb[k] = zp[(size_t)k * 8192 + 1];
        }
      }
#pragma unroll 1
      for (int io = 0; io < 2; ++io) {
#pragma unroll
        for (int k = 0; k < 4; ++k) {
          const int t = g8 * 8 + io * 4 + k;
          const int c = k & 1, p = c ^ 1;
          f32x4 acc[4];
          {
            half8 xlo = __builtin_bit_cast(half8, pa[k]);
            half8 xhi = __builtin_bit_cast(half8, pb[k]);
            acc[0] = (f32x4){(float)xlo[0], (float)xlo[1], (float)xlo[2], (float)xlo[3]};
            acc[1] = (f32x4){(float)xlo[4], (float)xlo[5], (float)xlo[6], (float)xlo[7]};
            acc[2] = (f32x4){(float)xhi[0], (float)xhi[1], (float)xhi[2], (float)xhi[3]};
            acc[3] = (f32x4){(float)xhi[4], (float)xhi[5], (float)xhi[6], (float)xhi[7]};
          }
          half8 B1[4];
#pragma unroll
          for (int s = 0; s < 4; ++s)
            B1[s] = *(const half8*)&sm.rc.h[p][n * 136 + s * 32 + q * 8];
#pragma unroll
          for (int s = 0; s < 4; ++s)
#pragma unroll
            for (int tl = 0; tl < 4; ++tl)
              acc[tl] = __builtin_amdgcn_mfma_f32_16x16x32_f16(WH[tl][s], B1[s], acc[tl], 0, 0, 0);

          float h1v[4];
          lstm_cell(acc, c1v, h1v);
          pool[0] += h1v[0]; pool[1] += h1v[1];
          pool[2] += h1v[2]; pool[3] += h1v[3];
          uint2 h1p;
          h1p.x = packh2f(h1v[0], h1v[1]);
          h1p.y = packh2f(h1v[2], h1v[3]);
          *(uint2*)&sm.rc.h[c][hoff] = h1p;
          const bool dopub = (io == 1) && (k == 3);
          __syncthreads();
          if (dopub && tid == 0)
            __hip_atomic_store(&l1_prog[b16], t + 1, __ATOMIC_RELEASE,
                               __HIP_MEMORY_SCOPE_AGENT);
          int tn = t + 4; if (tn > T_ - 1) tn = T_ - 1;
          const size_t so = (size_t)(tn & rmask2) * 8192;
          pa[k] = zp[so];
          pb[k] = zp[so + 1];
        }
      }
    }
    psave[(b16 * 8 + w) * 64 + L] = pool;
  } else if (bid < 16 + WCV) {
    // ---------------- conv + x0 projection workers ----------------
    const int wi = bid - 16;
    const int co = tid & 127;
    float cw[48];
#pragma unroll
    for (int i = 0; i < 12; ++i) {
      const float4 v = *(const float4*)(conv_w + co * 48 + i * 4);
      cw[i * 4 + 0] = v.x; cw[i * 4 + 1] = v.y;
      cw[i * 4 + 2] = v.z; cw[i * 4 + 3] = v.w;
    }
    const float cb = conv_b[co];
    half8 WB[4][4];
#pragma unroll
    for (int nt4 = 0; nt4 < 4; ++nt4)
#pragma unroll
      for (int s = 0; s < 4; ++s)
        WB[nt4][s] = __builtin_bit_cast(half8, WB0f[((w * 4 + nt4) * 4 + s) * 64 + L]);
    float b0v[4];
#pragma unroll
    for (int nt4 = 0; nt4 < 4; ++nt4) {
      int gg = (w * 4 + nt4) * 16 + n;
      b0v[nt4] = (b_ih0[gg] + b_hh0[gg]) * (((gg >> 7) == 2) ? L2E2 : L2E);
    }
    const int R = rmask + 1;

    for (int u = wi; u < 8192; u += WCV) {
      const int tile = u >> 7, b = u & 127;
      const int t0c = tile * 32;
      if (t0c + 32 > R) {
        const int need = t0c + 32 - R;
        if (tid == 0)
          while (__hip_atomic_load(&l0_prog[b >> 4], __ATOMIC_RELAXED,
                                   __HIP_MEMORY_SCOPE_AGENT) < need)
            __builtin_amdgcn_s_sleep(8);
      }
      __syncthreads();

      for (int idx = tid; idx < 544; idx += 512) {
        int row = idx >> 4, cc2 = idx & 15;
        int gt = t0c - 1 + row;
        sm.wk.xs[idx] = (gt >= 0 && gt < T_) ? x[((size_t)b * T_ + gt) * C_ + cc2] : 0.f;
      }
      __syncthreads();

#pragma unroll
      for (int pp = 0; pp < 8; ++pp) {
        int r = pp * 4 + (tid >> 7);
        float acc = cb;
#pragma unroll
        for (int c16 = 0; c16 < 16; ++c16)
#pragma unroll
          for (int kk = 0; kk < 3; ++kk)
            acc += sm.wk.xs[(r + kk) * 16 + c16] * cw[c16 * 3 + kk];
        acc = acc >= 0.f ? acc : 0.01f * acc;
        sm.wk.yh[r * 136 + co] = (_Float16)acc;
      }
      __syncthreads();

#pragma unroll
      for (int mt = 0; mt < 2; ++mt) {
        half8 A[4];
#pragma unroll
        for (int s = 0; s < 4; ++s)
          A[s] = *(const half8*)&sm.wk.yh[(mt * 16 + n) * 136 + s * 32 + q * 8];
#pragma unroll
        for (int nt4 = 0; nt4 < 4; ++nt4) {
          f32x4 acc = {b0v[nt4], b0v[nt4], b0v[nt4], b0v[nt4]};
#pragma unroll
          for (int s = 0; s < 4; ++s)
            acc = __builtin_amdgcn_mfma_f32_16x16x32_f16(A[s], WB[nt4][s], acc, 0, 0, 0);
          int tau = w * 4 + nt4;
          int off = (tau & 7) * 64 + (n >> 2) * 16 + (tau >> 3) * 4 + (n & 3);
#pragma unroll
          for (int reg = 0; reg < 4; ++reg)
            sm.wk.x0S[(mt * 16 + q * 4 + reg) * 512 + off] = (_Float16)acc[reg];
        }
      }
      __syncthreads();

      const int bn = b & 15, bb16 = b >> 4;
      const int trb = t0c & rmask;
#pragma unroll
      for (int kk = 0; kk < 2; ++kk) {
        int cc = kk * 512 + tid;
        int r = cc >> 5, wq = cc & 31;
        int w2 = wq >> 2, q2 = wq & 3;
        const uint4* src = (const uint4*)&sm.wk.x0S[r * 512 + wq * 16];
        size_t gidx = ((((size_t)(trb + r) * 8 + bb16) * 8 + w2) * 64 + (bn + 16 * q2)) * 2;
        x0f[gidx] = src[0];
        x0f[gidx + 1] = src[1];
      }
      asm volatile("s_waitcnt vmcnt(0)" ::: "memory");
      __syncthreads();
      if (tid == 0)
        __hip_atomic_fetch_add(&xready[tile * 8 + bb16], 1, __ATOMIC_RELEASE,
                               __HIP_MEMORY_SCOPE_AGENT);
    }
  } else {
    // ---------------- z1 workers: z1(t) = Wih1 . h0(t) + b1 ----------------
    const int wi = bid - (16 + WCV);
    half8 WI[4][4];
#pragma unroll
    for (int tl = 0; tl < 4; ++tl)
#pragma unroll
      for (int s = 0; s < 4; ++s)
        WI[tl][s] = __builtin_bit_cast(half8, Wih1f[((w * 4 + tl) * 4 + s) * 64 + L]);
    f32x4 b1v[4];
#pragma unroll
    for (int tl = 0; tl < 4; ++tl) b1v[tl] = b1fD[(w * 64 + L) * 4 + tl];
    const int R2 = rmask2 + 1;
    const _Float16* h0gh = (const _Float16*)h0g;

    for (int u = wi; u < 2048; u += WZ1) {
      const int t8 = u >> 3, b16 = u & 7;
      const int tend = t8 * 8 + 8;
      if (tid == 0) {
        while (__hip_atomic_load(&l0_prog[b16], __ATOMIC_ACQUIRE,
                                 __HIP_MEMORY_SCOPE_AGENT) < tend)
          __builtin_amdgcn_s_sleep(4);
        const int need = tend - R2;
        if (need > 0)
          while (__hip_atomic_load(&l1_prog[b16], __ATOMIC_RELAXED,
                                   __HIP_MEMORY_SCOPE_AGENT) < need)
            __builtin_amdgcn_s_sleep(8);
      }
      __syncthreads();

#pragma unroll 1
      for (int tt = 0; tt < 8; ++tt) {
        const int t = t8 * 8 + tt;
        const _Float16* hp = h0gh + ((size_t)(t * 8 + b16) * 16 + n) * 128 + q * 8;
        half8 Bf[4];
#pragma unroll
        for (int s = 0; s < 4; ++s) Bf[s] = *(const half8*)(hp + s * 32);
        f32x4 acc[4];
#pragma unroll
        for (int tl = 0; tl < 4; ++tl) acc[tl] = b1v[tl];
#pragma unroll
        for (int s = 0; s < 4; ++s)
#pragma unroll
          for (int tl = 0; tl < 4; ++tl)
            acc[tl] = __builtin_amdgcn_mfma_f32_16x16x32_f16(WI[tl][s], Bf[s], acc[tl], 0, 0, 0);
        uint4 o0, o1;
        o0.x = packh2f(acc[0][0], acc[0][1]); o0.y = packh2f(acc[0][2], acc[0][3]);
        o0.z = packh2f(acc[1][0], acc[1][1]); o0.w = packh2f(acc[1][2], acc[1][3]);
        o1.x = packh2f(acc[2][0], acc[2][1]); o1.y = packh2f(acc[2][2], acc[2][3]);
        o1.z = packh2f(acc[3][0], acc[3][1]); o1.w = packh2f(acc[3][2], acc[3][3]);
        uint4* dst = z1f + ((((size_t)(t & rmask2) * 8 + b16) * 8 + w) * 64 + L) * 2;
        dst[0] = o0;
        dst[1] = o1;
      }
      asm volatile("s_waitcnt vmcnt(0)" ::: "memory");
      __syncthreads();
      if (tid == 0)
        __hip_atomic_store(&z1r[u], 1, __ATOMIC_RELEASE,
                           __HIP_MEMORY_SCOPE_AGENT);
    }
  }
}

// ---------------------------------------------------------------------------
__global__ __launch_bounds__(128) void final_kernel(
    const f32x4* __restrict__ psave, const float* __restrict__ lin_w,
    const float* __restrict__ lin_b, float* __restrict__ out) {
  int b = threadIdx.x;
  int n = b & 15, b16 = b >> 4;
  float acc = 0.f;
  for (int w = 0; w < 8; ++w)
#pragma unroll
    for (int q = 0; q < 4; ++q) {
      f32x4 v = psave[(b16 * 8 + w) * 64 + n + 16 * q];
#pragma unroll
      for (int reg = 0; reg < 4; ++reg)
        acc += v[reg] * lin_w[w * 16 + q * 4 + reg];
    }
  out[b] = acc * (1.0f / (float)T_) + lin_b[0];
}

// ---------------------------------------------------------------------------
extern "C" void kernel_launch(void* const* d_in, const int* in_sizes, int n_in,
                              void* d_out, int out_size, void* d_ws, size_t ws_size,
                              hipStream_t stream) {
  (void)in_sizes; (void)n_in; (void)out_size;
  const float* x      = (const float*)d_in[0];
  const float* conv_w = (const float*)d_in[1];
  const float* conv_b = (const float*)d_in[2];
  const float* w_ih0  = (const float*)d_in[3];
  const float* w_hh0  = (const float*)d_in[4];
  const float* b_ih0  = (const float*)d_in[5];
  const float* b_hh0  = (const float*)d_in[6];
  const float* w_ih1  = (const float*)d_in[7];
  const float* w_hh1  = (const float*)d_in[8];
  const float* b_ih1  = (const float*)d_in[9];
  const float* b_hh1  = (const float*)d_in[10];
  const float* lin_w  = (const float*)d_in[11];
  const float* lin_b  = (const float*)d_in[12];

  char* ws = (char*)d_ws;
  uint4* Wf0   = (uint4*)(ws + 0);        // 131072
  uint4* Wih1f = (uint4*)(ws + 131072);   // 131072
  uint4* Whh1f = (uint4*)(ws + 262144);   // 131072
  uint4* WB0f  = (uint4*)(ws + 393216);   // 131072
  f32x4* b1fD  = (f32x4*)(ws + 524288);   // 32768
  f32x4* psave = (f32x4*)(ws + 557056);   // 65536
  int*   flags = (int*)(ws + 622592);     // 16384: xready[512]|l0[8]|l1[8]|z1r[2048]
  uint2* h0g   = (uint2*)(ws + 638976);   // 67108864 (full-T h0 stream)
  const size_t fixed = 638976 + 67108864; // 67747840

  int R = 256, R2 = 256;
  while (R > 64 &&
         fixed + ((size_t)R + (size_t)R2) * 131072 > ws_size) {
    R >>= 1; R2 >>= 1;
  }
  uint4* x0f = (uint4*)(ws + fixed);
  uint4* z1f = (uint4*)(ws + fixed + (size_t)R * 131072);

  int* xready  = flags;
  int* l0_prog = flags + 512;
  int* l1_prog = flags + 520;
  int* z1r     = flags + 528;

  hipMemsetAsync(flags, 0, 16384, stream);
  pack_kernel<<<136, 256, 0, stream>>>(w_ih0, w_hh0, w_ih1, w_hh1, b_ih1, b_hh1,
                                       Wf0, Wih1f, Whh1f, WB0f, b1fD);
  persist_kernel<<<NBLK, 512, 0, stream>>>(
      x, conv_w, conv_b, b_ih0, b_hh0, Wf0, Wih1f, Whh1f, WB0f, b1fD,
      x0f, h0g, z1f, psave, xready, l0_prog, l1_prog, z1r, R - 1, R2 - 1);
  final_kernel<<<1, 128, 0, stream>>>(psave, lin_w, lin_b, (float*)d_out);
}

// Round 7
// 2559.329 us; speedup vs baseline: 1.4132x; 1.4132x over previous
//
#include <hip/hip_runtime.h>
#include <hip/hip_fp16.h>
#include <cstdint>
#include <cstddef>

#define B_ 128
#define T_ 2048
#define C_ 16
#define CO_ 128
#define H_ 128
#define G_ 512
#define WCV 240                 // conv/x0 worker blocks
#define NBLK (16 + WCV)         // 256
#define L2E  1.4426950408889634f
#define L2E2 2.8853900817779268f

typedef _Float16 half8 __attribute__((ext_vector_type(8)));
typedef float f32x4 __attribute__((ext_vector_type(4)));

__device__ __forceinline__ unsigned packh2f(float a, float b) {
  union { _Float16 h[2]; unsigned u; } x;
  x.h[0] = (_Float16)a; x.h[1] = (_Float16)b;
  return x.u;
}

__device__ __forceinline__ float rcpf(float x) { return __builtin_amdgcn_rcpf(x); }

__device__ __forceinline__ float exp2f_(float x) {
#if __has_builtin(__builtin_amdgcn_exp2f)
  return __builtin_amdgcn_exp2f(x);
#else
  return __expf(x * 0.6931471805599453f);
#endif
}

// Gates arrive PRE-SCALED: i,f,o by log2e; g by 2*log2e.
__device__ __forceinline__ void lstm_cell(const f32x4* acc, f32x4& c, float* h) {
#pragma unroll
  for (int r = 0; r < 4; ++r) {
    float iv = acc[0][r], fv = acc[1][r], gv = acc[2][r], ov = acc[3][r];
    gv = fminf(fmaxf(gv, -43.3f), 43.3f);
    float ei = exp2f_(-iv), ef = exp2f_(-fv), eg = exp2f_(gv);
    float P = (1.f + ei) * (eg + 1.f);   // sig(i)*tanh(g) = (eg-1)/P
    float Q = 1.f + ef;                  // sig(f) = 1/Q
    float num = c[r] * P + (eg - 1.f) * Q;
    float cN = num * rcpf(Q * P);
    c[r] = cN;
    float cc = fminf(fmaxf(cN, -15.f), 15.f);
    float eo = exp2f_(-ov), ec = exp2f_(L2E2 * cc);
    h[r] = (ec - 1.f) * rcpf((1.f + eo) * (ec + 1.f));
  }
}

// ---------------------------------------------------------------------------
// pack_kernel: fragment-ordered weight buffers, rows pre-scaled by log2e /
// 2*log2e (g gate) so the cell can use raw exp2.
// ---------------------------------------------------------------------------
__global__ __launch_bounds__(256) void pack_kernel(
    const float* __restrict__ w_ih0, const float* __restrict__ w_hh0,
    const float* __restrict__ w_ih1, const float* __restrict__ w_hh1,
    const float* __restrict__ b_ih1, const float* __restrict__ b_hh1,
    uint4* __restrict__ Wf0, uint4* __restrict__ Wih1f,
    uint4* __restrict__ Whh1f, uint4* __restrict__ WB0f,
    f32x4* __restrict__ b1fD) {
  int tid = blockIdx.x * 256 + threadIdx.x;
  if (tid < 24576) {
    int u = tid & 8191, L = u & 63, s = (u >> 6) & 3, tl = (u >> 8) & 3, w = u >> 10;
    int which = tid >> 13;
    const float* src = (which == 0) ? w_hh0 : (which == 1) ? w_ih1 : w_hh1;
    uint4* dst = (which == 0) ? Wf0 : (which == 1) ? Wih1f : Whh1f;
    int m = (w + 8 * tl) * 16 + (L & 15);     // gate index == tl
    float sc = (tl == 2) ? L2E2 : L2E;
    int k0 = s * 32 + (L >> 4) * 8;
    const float* p = src + m * 128 + k0;
    uint4 o;
    o.x = packh2f(p[0] * sc, p[1] * sc); o.y = packh2f(p[2] * sc, p[3] * sc);
    o.z = packh2f(p[4] * sc, p[5] * sc); o.w = packh2f(p[6] * sc, p[7] * sc);
    dst[u] = o;
  } else if (tid < 32768) {
    int u = tid - 24576, L = u & 63, s = (u >> 6) & 3, nt = u >> 8;
    int g = nt * 16 + (L & 15);
    float sc = ((nt >> 3) == 2) ? L2E2 : L2E;
    int k0 = s * 32 + (L >> 4) * 8;
    const float* p = w_ih0 + g * 128 + k0;
    uint4 o;
    o.x = packh2f(p[0] * sc, p[1] * sc); o.y = packh2f(p[2] * sc, p[3] * sc);
    o.z = packh2f(p[4] * sc, p[5] * sc); o.w = packh2f(p[6] * sc, p[7] * sc);
    WB0f[u] = o;
  } else if (tid < 34816) {
    int u2 = tid - 32768;
    int tl = u2 & 3, L = (u2 >> 2) & 63, w = u2 >> 8;
    int q = L >> 4;
    float sc = (tl == 2) ? L2E2 : L2E;
    f32x4 o;
#pragma unroll
    for (int reg = 0; reg < 4; ++reg) {
      int row = (w + 8 * tl) * 16 + q * 4 + reg;
      o[reg] = (b_ih1[row] + b_hh1[row]) * sc;
    }
    b1fD[u2] = o;
  }
}

// ---------------------------------------------------------------------------
// persist_kernel:
//  blocks 0..7   : layer-0 recurrence + fused z1 = b1 + Wih1.h0 (shares the
//                  per-step B-fragment with Whh0 — zero extra LDS traffic)
//  blocks 8..15  : layer-1 recurrence (Whh1 only; z1 from ring, single hop)
//  blocks 16..   : conv+x0 producers (x0 ring, 32-step tiles)
// Flags: xready[64*8], l0_prog[8] (= z1 steps published), l1_prog[8].
// ---------------------------------------------------------------------------
__global__ __launch_bounds__(512, 2) void persist_kernel(
    const float* __restrict__ x, const float* __restrict__ conv_w,
    const float* __restrict__ conv_b, const float* __restrict__ b_ih0,
    const float* __restrict__ b_hh0,
    const uint4* __restrict__ Wf0, const uint4* __restrict__ Wih1f,
    const uint4* __restrict__ Whh1f, const uint4* __restrict__ WB0f,
    const f32x4* __restrict__ b1fD,
    uint4* __restrict__ x0f, uint4* __restrict__ z1f,
    f32x4* __restrict__ psave,
    int* __restrict__ xready, int* __restrict__ l0_prog,
    int* __restrict__ l1_prog, int rmask, int rmask2) {
  __shared__ __align__(16) union {
    struct { float xs[34 * 16]; _Float16 yh[32 * 136]; _Float16 x0S[32 * 512]; } wk;
    struct { _Float16 h[2][16 * 136]; } rc;
  } sm;

  const int bid = blockIdx.x;
  const int tid = threadIdx.x;
  const int w = tid >> 6, L = tid & 63, q = L >> 4, n = L & 15;

  if (bid < 8) {
    // ---------------- layer-0 recurrence + fused z1 production --------------
    const int b16 = bid;
    half8 WA0[4][4], WI1[4][4];
#pragma unroll
    for (int tl = 0; tl < 4; ++tl)
#pragma unroll
      for (int s = 0; s < 4; ++s) {
        WA0[tl][s] = __builtin_bit_cast(half8, Wf0[((w * 4 + tl) * 4 + s) * 64 + L]);
        WI1[tl][s] = __builtin_bit_cast(half8, Wih1f[((w * 4 + tl) * 4 + s) * 64 + L]);
      }
    f32x4 b1v[4];
#pragma unroll
    for (int tl = 0; tl < 4; ++tl) b1v[tl] = b1fD[(w * 64 + L) * 4 + tl];

    f32x4 c0v = {0.f, 0.f, 0.f, 0.f};
    const int hoff = n * 136 + w * 16 + q * 4;
    *(uint2*)&sm.rc.h[1][hoff] = make_uint2(0u, 0u);
    __syncthreads();

    const uint4* xp = x0f + (((size_t)b16 * 8 + w) * 64 + L) * 2;
    uint4* zbase = z1f + ((size_t)b16 * 8 + w) * 128 + L * 2;
    const int R2 = rmask2 + 1;
    uint4 pa[2], pb[2];

    for (int g = 0; g < 64; ++g) {
      if (tid == 0) {
        while (__hip_atomic_load(&xready[g * 8 + b16], __ATOMIC_ACQUIRE,
                                 __HIP_MEMORY_SCOPE_AGENT) < 16)
          __builtin_amdgcn_s_sleep(2);
        if (g < 63)
          while (__hip_atomic_load(&xready[(g + 1) * 8 + b16], __ATOMIC_ACQUIRE,
                                   __HIP_MEMORY_SCOPE_AGENT) < 16)
            __builtin_amdgcn_s_sleep(2);
        const int need = 32 * g + 32 - R2;   // z1 ring back-pressure
        if (need > 0)
          while (__hip_atomic_load(&l1_prog[b16], __ATOMIC_RELAXED,
                                   __HIP_MEMORY_SCOPE_AGENT) < need)
            __builtin_amdgcn_s_sleep(8);
      }
      __syncthreads();
      if (g == 0) {
        pa[0] = xp[0]; pb[0] = xp[1];
        pa[1] = xp[8192]; pb[1] = xp[8193];
      }
#pragma unroll 1
      for (int io = 0; io < 8; ++io) {
#pragma unroll
        for (int k = 0; k < 4; ++k) {
          const int t = g * 32 + io * 4 + k;
          const int c = k & 1, p = c ^ 1, j = k & 1;
          f32x4 acc[4];
          {
            half8 xlo = __builtin_bit_cast(half8, pa[j]);
            half8 xhi = __builtin_bit_cast(half8, pb[j]);
            acc[0] = (f32x4){(float)xlo[0], (float)xlo[1], (float)xlo[2], (float)xlo[3]};
            acc[1] = (f32x4){(float)xlo[4], (float)xlo[5], (float)xlo[6], (float)xlo[7]};
            acc[2] = (f32x4){(float)xhi[0], (float)xhi[1], (float)xhi[2], (float)xhi[3]};
            acc[3] = (f32x4){(float)xhi[4], (float)xhi[5], (float)xhi[6], (float)xhi[7]};
          }
          half8 B0[4];
#pragma unroll
          for (int s = 0; s < 4; ++s)
            B0[s] = *(const half8*)&sm.rc.h[p][n * 136 + s * 32 + q * 8];
          // recurrent matmul (feeds cell this step)
#pragma unroll
          for (int s = 0; s < 4; ++s)
#pragma unroll
            for (int tl = 0; tl < 4; ++tl)
              acc[tl] = __builtin_amdgcn_mfma_f32_16x16x32_f16(WA0[tl][s], B0[s], acc[tl], 0, 0, 0);
          // z1(t-1) = b1 + Wih1 . h0(t-1) — same B operand, off critical dep
          f32x4 accW[4];
#pragma unroll
          for (int tl = 0; tl < 4; ++tl) accW[tl] = b1v[tl];
#pragma unroll
          for (int s = 0; s < 4; ++s)
#pragma unroll
            for (int tl = 0; tl < 4; ++tl)
              accW[tl] = __builtin_amdgcn_mfma_f32_16x16x32_f16(WI1[tl][s], B0[s], accW[tl], 0, 0, 0);

          // x0 prefetch (depth 2)
          {
            int tn = t + 2; if (tn > T_ - 1) tn = T_ - 1;
            const size_t so = (size_t)(tn & rmask) * 8192;
            pa[j] = xp[so];
            pb[j] = xp[so + 1];
          }

          float h0v[4];
          lstm_cell(acc, c0v, h0v);
          uint2 h0p;
          h0p.x = packh2f(h0v[0], h0v[1]);
          h0p.y = packh2f(h0v[2], h0v[3]);
          *(uint2*)&sm.rc.h[c][hoff] = h0p;

          if (t > 0) {
            uint4 o0, o1;
            o0.x = packh2f(accW[0][0], accW[0][1]); o0.y = packh2f(accW[0][2], accW[0][3]);
            o0.z = packh2f(accW[1][0], accW[1][1]); o0.w = packh2f(accW[1][2], accW[1][3]);
            o1.x = packh2f(accW[2][0], accW[2][1]); o1.y = packh2f(accW[2][2], accW[2][3]);
            o1.z = packh2f(accW[3][0], accW[3][1]); o1.w = packh2f(accW[3][2], accW[3][3]);
            const size_t zs = (size_t)((t - 1) & rmask2) * 8192;
            zbase[zs] = o0;
            zbase[zs + 1] = o1;
          }

          const bool dopub = (io & 1) && (k == 3);
          if (dopub) asm volatile("s_waitcnt vmcnt(0)" ::: "memory");
          __syncthreads();
          if (dopub && tid == 0)
            __hip_atomic_store(&l0_prog[b16], t, __ATOMIC_RELEASE,
                               __HIP_MEMORY_SCOPE_AGENT);  // z1 avail through t-1
        }
      }
    }
    // epilogue: z1(T-1) from final h0 (in hb[1], since (T-1)&1 == 1)
    {
      half8 B0[4];
#pragma unroll
      for (int s = 0; s < 4; ++s)
        B0[s] = *(const half8*)&sm.rc.h[1][n * 136 + s * 32 + q * 8];
      f32x4 accW[4];
#pragma unroll
      for (int tl = 0; tl < 4; ++tl) accW[tl] = b1v[tl];
#pragma unroll
      for (int s = 0; s < 4; ++s)
#pragma unroll
        for (int tl = 0; tl < 4; ++tl)
          accW[tl] = __builtin_amdgcn_mfma_f32_16x16x32_f16(WI1[tl][s], B0[s], accW[tl], 0, 0, 0);
      uint4 o0, o1;
      o0.x = packh2f(accW[0][0], accW[0][1]); o0.y = packh2f(accW[0][2], accW[0][3]);
      o0.z = packh2f(accW[1][0], accW[1][1]); o0.w = packh2f(accW[1][2], accW[1][3]);
      o1.x = packh2f(accW[2][0], accW[2][1]); o1.y = packh2f(accW[2][2], accW[2][3]);
      o1.z = packh2f(accW[3][0], accW[3][1]); o1.w = packh2f(accW[3][2], accW[3][3]);
      const size_t zs = (size_t)((T_ - 1) & rmask2) * 8192;
      zbase[zs] = o0;
      zbase[zs + 1] = o1;
      asm volatile("s_waitcnt vmcnt(0)" ::: "memory");
      __syncthreads();
      if (tid == 0)
        __hip_atomic_store(&l0_prog[b16], T_, __ATOMIC_RELEASE,
                           __HIP_MEMORY_SCOPE_AGENT);
    }
  } else if (bid < 16) {
    // ---------------- layer-1 recurrence (Whh1 only) ----------------
    const int b16 = bid - 8;
    half8 WH[4][4];
#pragma unroll
    for (int tl = 0; tl < 4; ++tl)
#pragma unroll
      for (int s = 0; s < 4; ++s)
        WH[tl][s] = __builtin_bit_cast(half8, Whh1f[((w * 4 + tl) * 4 + s) * 64 + L]);

    f32x4 c1v = {0.f, 0.f, 0.f, 0.f};
    f32x4 pool = {0.f, 0.f, 0.f, 0.f};
    const int hoff = n * 136 + w * 16 + q * 4;
    *(uint2*)&sm.rc.h[1][hoff] = make_uint2(0u, 0u);
    __syncthreads();

    const uint4* zp = z1f + (((size_t)b16 * 8 + w) * 64 + L) * 2;
    uint4 pa[4], pb[4];

    for (int g8 = 0; g8 < 256; ++g8) {
      const int p0 = g8 * 8;
      int tgt = p0 + 12; if (tgt > T_) tgt = T_;
      if (tid == 0)
        while (__hip_atomic_load(&l0_prog[b16], __ATOMIC_ACQUIRE,
                                 __HIP_MEMORY_SCOPE_AGENT) < tgt)
          __builtin_amdgcn_s_sleep(2);
      __syncthreads();
      if (g8 == 0) {
#pragma unroll
        for (int k = 0; k < 4; ++k) {
          pa[k] = zp[(size_t)k * 8192];
          pb[k] = zp[(size_t)k * 8192 + 1];
        }
      }
#pragma unroll 1
      for (int io = 0; io < 2; ++io) {
#pragma unroll
        for (int k = 0; k < 4; ++k) {
          const int t = p0 + io * 4 + k;
          const int c = k & 1, p = c ^ 1;
          f32x4 acc[4];
          {
            half8 xlo = __builtin_bit_cast(half8, pa[k]);
            half8 xhi = __builtin_bit_cast(half8, pb[k]);
            acc[0] = (f32x4){(float)xlo[0], (float)xlo[1], (float)xlo[2], (float)xlo[3]};
            acc[1] = (f32x4){(float)xlo[4], (float)xlo[5], (float)xlo[6], (float)xlo[7]};
            acc[2] = (f32x4){(float)xhi[0], (float)xhi[1], (float)xhi[2], (float)xhi[3]};
            acc[3] = (f32x4){(float)xhi[4], (float)xhi[5], (float)xhi[6], (float)xhi[7]};
          }
          half8 B1[4];
#pragma unroll
          for (int s = 0; s < 4; ++s)
            B1[s] = *(const half8*)&sm.rc.h[p][n * 136 + s * 32 + q * 8];
#pragma unroll
          for (int s = 0; s < 4; ++s)
#pragma unroll
            for (int tl = 0; tl < 4; ++tl)
              acc[tl] = __builtin_amdgcn_mfma_f32_16x16x32_f16(WH[tl][s], B1[s], acc[tl], 0, 0, 0);

          {
            int tn = t + 4; if (tn > T_ - 1) tn = T_ - 1;
            const size_t so = (size_t)(tn & rmask2) * 8192;
            pa[k] = zp[so];
            pb[k] = zp[so + 1];
          }

          float h1v[4];
          lstm_cell(acc, c1v, h1v);
          pool[0] += h1v[0]; pool[1] += h1v[1];
          pool[2] += h1v[2]; pool[3] += h1v[3];
          uint2 h1p;
          h1p.x = packh2f(h1v[0], h1v[1]);
          h1p.y = packh2f(h1v[2], h1v[3]);
          *(uint2*)&sm.rc.h[c][hoff] = h1p;
          const bool dopub = (io == 1) && (k == 3);
          __syncthreads();
          if (dopub && tid == 0)
            __hip_atomic_store(&l1_prog[b16], t + 1, __ATOMIC_RELEASE,
                               __HIP_MEMORY_SCOPE_AGENT);
        }
      }
    }
    psave[(b16 * 8 + w) * 64 + L] = pool;
  } else {
    // ---------------- conv + x0 projection workers ----------------
    const int wi = bid - 16;
    const int co = tid & 127;
    float cw[48];
#pragma unroll
    for (int i = 0; i < 12; ++i) {
      const float4 v = *(const float4*)(conv_w + co * 48 + i * 4);
      cw[i * 4 + 0] = v.x; cw[i * 4 + 1] = v.y;
      cw[i * 4 + 2] = v.z; cw[i * 4 + 3] = v.w;
    }
    const float cb = conv_b[co];
    half8 WB[4][4];
#pragma unroll
    for (int nt4 = 0; nt4 < 4; ++nt4)
#pragma unroll
      for (int s = 0; s < 4; ++s)
        WB[nt4][s] = __builtin_bit_cast(half8, WB0f[((w * 4 + nt4) * 4 + s) * 64 + L]);
    float b0v[4];
#pragma unroll
    for (int nt4 = 0; nt4 < 4; ++nt4) {
      int gg = (w * 4 + nt4) * 16 + n;
      b0v[nt4] = (b_ih0[gg] + b_hh0[gg]) * (((gg >> 7) == 2) ? L2E2 : L2E);
    }
    const int R = rmask + 1;

    for (int u = wi; u < 8192; u += WCV) {
      const int tile = u >> 7, b = u & 127;
      const int t0c = tile * 32;
      if (t0c + 32 > R) {
        const int need = t0c + 32 - R;
        if (tid == 0)
          while (__hip_atomic_load(&l0_prog[b >> 4], __ATOMIC_RELAXED,
                                   __HIP_MEMORY_SCOPE_AGENT) < need)
            __builtin_amdgcn_s_sleep(8);
      }
      __syncthreads();

      for (int idx = tid; idx < 544; idx += 512) {
        int row = idx >> 4, cc2 = idx & 15;
        int gt = t0c - 1 + row;
        sm.wk.xs[idx] = (gt >= 0 && gt < T_) ? x[((size_t)b * T_ + gt) * C_ + cc2] : 0.f;
      }
      __syncthreads();

#pragma unroll
      for (int pp = 0; pp < 8; ++pp) {
        int r = pp * 4 + (tid >> 7);
        float acc = cb;
#pragma unroll
        for (int c16 = 0; c16 < 16; ++c16)
#pragma unroll
          for (int kk = 0; kk < 3; ++kk)
            acc += sm.wk.xs[(r + kk) * 16 + c16] * cw[c16 * 3 + kk];
        acc = acc >= 0.f ? acc : 0.01f * acc;
        sm.wk.yh[r * 136 + co] = (_Float16)acc;
      }
      __syncthreads();

#pragma unroll
      for (int mt = 0; mt < 2; ++mt) {
        half8 A[4];
#pragma unroll
        for (int s = 0; s < 4; ++s)
          A[s] = *(const half8*)&sm.wk.yh[(mt * 16 + n) * 136 + s * 32 + q * 8];
#pragma unroll
        for (int nt4 = 0; nt4 < 4; ++nt4) {
          f32x4 acc = {b0v[nt4], b0v[nt4], b0v[nt4], b0v[nt4]};
#pragma unroll
          for (int s = 0; s < 4; ++s)
            acc = __builtin_amdgcn_mfma_f32_16x16x32_f16(A[s], WB[nt4][s], acc, 0, 0, 0);
          int tau = w * 4 + nt4;
          int off = (tau & 7) * 64 + (n >> 2) * 16 + (tau >> 3) * 4 + (n & 3);
#pragma unroll
          for (int reg = 0; reg < 4; ++reg)
            sm.wk.x0S[(mt * 16 + q * 4 + reg) * 512 + off] = (_Float16)acc[reg];
        }
      }
      __syncthreads();

      const int bn = b & 15, bb16 = b >> 4;
      const int trb = t0c & rmask;
#pragma unroll
      for (int kk = 0; kk < 2; ++kk) {
        int cc = kk * 512 + tid;
        int r = cc >> 5, wq = cc & 31;
        int w2 = wq >> 2, q2 = wq & 3;
        const uint4* src = (const uint4*)&sm.wk.x0S[r * 512 + wq * 16];
        size_t gidx = ((((size_t)(trb + r) * 8 + bb16) * 8 + w2) * 64 + (bn + 16 * q2)) * 2;
        x0f[gidx] = src[0];
        x0f[gidx + 1] = src[1];
      }
      asm volatile("s_waitcnt vmcnt(0)" ::: "memory");
      __syncthreads();
      if (tid == 0)
        __hip_atomic_fetch_add(&xready[tile * 8 + bb16], 1, __ATOMIC_RELEASE,
                               __HIP_MEMORY_SCOPE_AGENT);
    }
  }
}

// ---------------------------------------------------------------------------
__global__ __launch_bounds__(128) void final_kernel(
    const f32x4* __restrict__ psave, const float* __restrict__ lin_w,
    const float* __restrict__ lin_b, float* __restrict__ out) {
  int b = threadIdx.x;
  int n = b & 15, b16 = b >> 4;
  float acc = 0.f;
  for (int w = 0; w < 8; ++w)
#pragma unroll
    for (int q = 0; q < 4; ++q) {
      f32x4 v = psave[(b16 * 8 + w) * 64 + n + 16 * q];
#pragma unroll
      for (int reg = 0; reg < 4; ++reg)
        acc += v[reg] * lin_w[w * 16 + q * 4 + reg];
    }
  out[b] = acc * (1.0f / (float)T_) + lin_b[0];
}

// ---------------------------------------------------------------------------
extern "C" void kernel_launch(void* const* d_in, const int* in_sizes, int n_in,
                              void* d_out, int out_size, void* d_ws, size_t ws_size,
                              hipStream_t stream) {
  (void)in_sizes; (void)n_in; (void)out_size;
  const float* x      = (const float*)d_in[0];
  const float* conv_w = (const float*)d_in[1];
  const float* conv_b = (const float*)d_in[2];
  const float* w_ih0  = (const float*)d_in[3];
  const float* w_hh0  = (const float*)d_in[4];
  const float* b_ih0  = (const float*)d_in[5];
  const float* b_hh0  = (const float*)d_in[6];
  const float* w_ih1  = (const float*)d_in[7];
  const float* w_hh1  = (const float*)d_in[8];
  const float* b_ih1  = (const float*)d_in[9];
  const float* b_hh1  = (const float*)d_in[10];
  const float* lin_w  = (const float*)d_in[11];
  const float* lin_b  = (const float*)d_in[12];

  char* ws = (char*)d_ws;
  uint4* Wf0   = (uint4*)(ws + 0);        // 131072
  uint4* Wih1f = (uint4*)(ws + 131072);   // 131072
  uint4* Whh1f = (uint4*)(ws + 262144);   // 131072
  uint4* WB0f  = (uint4*)(ws + 393216);   // 131072
  f32x4* b1fD  = (f32x4*)(ws + 524288);   // 32768
  f32x4* psave = (f32x4*)(ws + 557056);   // 65536
  int*   flags = (int*)(ws + 622592);     // 4096: xready[512]|l0[8]|l1[8]
  const size_t base = 626688;

  int R = 512, R2 = 256;  // x0 ring, z1 ring (steps)
  while (R > 64 && base + ((size_t)R + (size_t)R2) * 131072 > ws_size) {
    R >>= 1;
    if (R2 > R) R2 = R;
  }
  uint4* x0f = (uint4*)(ws + base);
  uint4* z1f = (uint4*)(ws + base + (size_t)R * 131072);

  int* xready  = flags;
  int* l0_prog = flags + 512;
  int* l1_prog = flags + 520;

  hipMemsetAsync(flags, 0, 4096, stream);
  pack_kernel<<<136, 256, 0, stream>>>(w_ih0, w_hh0, w_ih1, w_hh1, b_ih1, b_hh1,
                                       Wf0, Wih1f, Whh1f, WB0f, b1fD);
  persist_kernel<<<NBLK, 512, 0, stream>>>(
      x, conv_w, conv_b, b_ih0, b_hh0, Wf0, Wih1f, Whh1f, WB0f, b1fD,
      x0f, z1f, psave, xready, l0_prog, l1_prog, R - 1, R2 - 1);
  final_kernel<<<1, 128, 0, stream>>>(psave, lin_w, lin_b, (float*)d_out);
}

// Round 8
// 2094.722 us; speedup vs baseline: 1.7266x; 1.2218x over previous
//
#include <hip/hip_runtime.h>
#include <hip/hip_fp16.h>
#include <cstdint>
#include <cstddef>

#define B_ 128
#define T_ 2048
#define C_ 16
#define CO_ 128
#define H_ 128
#define G_ 512
#define WCV 232                 // conv/x0 worker blocks
#define NBLK (24 + WCV)         // 256 = 8 L0 + 8 Z1 + 8 L1 + workers
#define L2E  1.4426950408889634f
#define L2E2 2.8853900817779268f

typedef _Float16 half8 __attribute__((ext_vector_type(8)));
typedef float f32x4 __attribute__((ext_vector_type(4)));

__device__ __forceinline__ unsigned packh2f(float a, float b) {
  union { _Float16 h[2]; unsigned u; } x;
  x.h[0] = (_Float16)a; x.h[1] = (_Float16)b;
  return x.u;
}

__device__ __forceinline__ float rcpf(float x) { return __builtin_amdgcn_rcpf(x); }

__device__ __forceinline__ float exp2f_(float x) {
#if __has_builtin(__builtin_amdgcn_exp2f)
  return __builtin_amdgcn_exp2f(x);
#else
  return __expf(x * 0.6931471805599453f);
#endif
}

// Gates arrive PRE-SCALED: i,f,o by log2e; g by 2*log2e.
__device__ __forceinline__ void lstm_cell(const f32x4* acc, f32x4& c, float* h) {
#pragma unroll
  for (int r = 0; r < 4; ++r) {
    float iv = acc[0][r], fv = acc[1][r], gv = acc[2][r], ov = acc[3][r];
    gv = fminf(fmaxf(gv, -43.3f), 43.3f);
    float ei = exp2f_(-iv), ef = exp2f_(-fv), eg = exp2f_(gv);
    float P = (1.f + ei) * (eg + 1.f);
    float Q = 1.f + ef;
    float num = c[r] * P + (eg - 1.f) * Q;
    float cN = num * rcpf(Q * P);
    c[r] = cN;
    float cc = fminf(fmaxf(cN, -15.f), 15.f);
    float eo = exp2f_(-ov), ec = exp2f_(L2E2 * cc);
    h[r] = (ec - 1.f) * rcpf((1.f + eo) * (ec + 1.f));
  }
}

// ---------------------------------------------------------------------------
// pack_kernel: fragment-ordered weight buffers (pre-scaled by log2e / 2log2e).
// ---------------------------------------------------------------------------
__global__ __launch_bounds__(256) void pack_kernel(
    const float* __restrict__ w_ih0, const float* __restrict__ w_hh0,
    const float* __restrict__ w_ih1, const float* __restrict__ w_hh1,
    const float* __restrict__ b_ih1, const float* __restrict__ b_hh1,
    uint4* __restrict__ Wf0, uint4* __restrict__ Wih1f,
    uint4* __restrict__ Whh1f, uint4* __restrict__ WB0f,
    f32x4* __restrict__ b1fD) {
  int tid = blockIdx.x * 256 + threadIdx.x;
  if (tid < 24576) {
    int u = tid & 8191, L = u & 63, s = (u >> 6) & 3, tl = (u >> 8) & 3, w = u >> 10;
    int which = tid >> 13;
    const float* src = (which == 0) ? w_hh0 : (which == 1) ? w_ih1 : w_hh1;
    uint4* dst = (which == 0) ? Wf0 : (which == 1) ? Wih1f : Whh1f;
    int m = (w + 8 * tl) * 16 + (L & 15);
    float sc = (tl == 2) ? L2E2 : L2E;
    int k0 = s * 32 + (L >> 4) * 8;
    const float* p = src + m * 128 + k0;
    uint4 o;
    o.x = packh2f(p[0] * sc, p[1] * sc); o.y = packh2f(p[2] * sc, p[3] * sc);
    o.z = packh2f(p[4] * sc, p[5] * sc); o.w = packh2f(p[6] * sc, p[7] * sc);
    dst[u] = o;
  } else if (tid < 32768) {
    int u = tid - 24576, L = u & 63, s = (u >> 6) & 3, nt = u >> 8;
    int g = nt * 16 + (L & 15);
    float sc = ((nt >> 3) == 2) ? L2E2 : L2E;
    int k0 = s * 32 + (L >> 4) * 8;
    const float* p = w_ih0 + g * 128 + k0;
    uint4 o;
    o.x = packh2f(p[0] * sc, p[1] * sc); o.y = packh2f(p[2] * sc, p[3] * sc);
    o.z = packh2f(p[4] * sc, p[5] * sc); o.w = packh2f(p[6] * sc, p[7] * sc);
    WB0f[u] = o;
  } else if (tid < 34816) {
    int u2 = tid - 32768;
    int tl = u2 & 3, L = (u2 >> 2) & 63, w = u2 >> 8;
    int q = L >> 4;
    float sc = (tl == 2) ? L2E2 : L2E;
    f32x4 o;
#pragma unroll
    for (int reg = 0; reg < 4; ++reg) {
      int row = (w + 8 * tl) * 16 + q * 4 + reg;
      o[reg] = (b_ih1[row] + b_hh1[row]) * sc;
    }
    b1fD[u2] = o;
  }
}

// ---------------------------------------------------------------------------
// persist_kernel — 3-stage chain + producers:
//  bid 0..7  : L0  (Whh0 + cell0; h0 -> LDS + h0g; publishes l0_prog /4 steps)
//  bid 8..15 : Z1  (z1 = b1 + Wih1.h0 from h0g, 4-step windows -> z1f ring)
//  bid 16..23: L1  (Whh1 + cell1 + pool; consumes z1f ring)
//  bid 24..  : conv+x0 producers (x0 ring, BP on coarse flag)
// All flags one per 64B line: base + b16*16.
// ---------------------------------------------------------------------------
__global__ __launch_bounds__(512, 2) void persist_kernel(
    const float* __restrict__ x, const float* __restrict__ conv_w,
    const float* __restrict__ conv_b, const float* __restrict__ b_ih0,
    const float* __restrict__ b_hh0,
    const uint4* __restrict__ Wf0, const uint4* __restrict__ Wih1f,
    const uint4* __restrict__ Whh1f, const uint4* __restrict__ WB0f,
    const f32x4* __restrict__ b1fD,
    uint4* __restrict__ x0f, uint2* __restrict__ h0g, uint4* __restrict__ z1f,
    f32x4* __restrict__ psave, int* __restrict__ flags,
    int rmask, int rmask2) {
  __shared__ __align__(16) union {
    struct { float xs[34 * 16]; _Float16 yh[32 * 136]; _Float16 x0S[32 * 512]; } wk;
    struct { _Float16 h[2][16 * 136]; } rc;
  } sm;

  int* xready = flags;          // [tile*8 + b16], 512 ints
  int* l0p = flags + 512;       // + b16*16
  int* l0c = flags + 640;       // + b16*16
  int* z1p = flags + 768;       // + b16*16
  int* l1p = flags + 896;       // + b16*16

  const int bid = blockIdx.x;
  const int tid = threadIdx.x;
  const int w = tid >> 6, L = tid & 63, q = L >> 4, n = L & 15;

  if (bid < 8) {
    // ---------------- L0: layer-0 recurrence ----------------
    const int b16 = bid;
    half8 WA0[4][4];
#pragma unroll
    for (int tl = 0; tl < 4; ++tl)
#pragma unroll
      for (int s = 0; s < 4; ++s)
        WA0[tl][s] = __builtin_bit_cast(half8, Wf0[((w * 4 + tl) * 4 + s) * 64 + L]);

    f32x4 c0v = {0.f, 0.f, 0.f, 0.f};
    const int hoff = n * 136 + w * 16 + q * 4;
    *(uint2*)&sm.rc.h[1][hoff] = make_uint2(0u, 0u);
    __syncthreads();

    const uint4* xp = x0f + (((size_t)b16 * 8 + w) * 64 + L) * 2;
    uint2* hg = h0g + ((b16 * 16 + n) * 32 + w * 4 + q);
    uint4 pa[4], pb[4];

    for (int g = 0; g < 64; ++g) {
      if (tid == 0) {
        while (__hip_atomic_load(&xready[g * 8 + b16], __ATOMIC_ACQUIRE,
                                 __HIP_MEMORY_SCOPE_AGENT) < 16)
          __builtin_amdgcn_s_sleep(2);
        if (g < 63)
          while (__hip_atomic_load(&xready[(g + 1) * 8 + b16], __ATOMIC_ACQUIRE,
                                   __HIP_MEMORY_SCOPE_AGENT) < 16)
            __builtin_amdgcn_s_sleep(2);
      }
      __syncthreads();
      if (g == 0) {
#pragma unroll
        for (int k = 0; k < 4; ++k) {
          pa[k] = xp[(size_t)k * 8192];
          pb[k] = xp[(size_t)k * 8192 + 1];
        }
      }
#pragma unroll 1
      for (int io = 0; io < 8; ++io) {
#pragma unroll
        for (int k = 0; k < 4; ++k) {
          const int t = g * 32 + io * 4 + k;
          const int c = t & 1, p = c ^ 1;
          f32x4 acc[4];
          {
            half8 xlo = __builtin_bit_cast(half8, pa[k]);
            half8 xhi = __builtin_bit_cast(half8, pb[k]);
            acc[0] = (f32x4){(float)xlo[0], (float)xlo[1], (float)xlo[2], (float)xlo[3]};
            acc[1] = (f32x4){(float)xlo[4], (float)xlo[5], (float)xlo[6], (float)xlo[7]};
            acc[2] = (f32x4){(float)xhi[0], (float)xhi[1], (float)xhi[2], (float)xhi[3]};
            acc[3] = (f32x4){(float)xhi[4], (float)xhi[5], (float)xhi[6], (float)xhi[7]};
          }
          half8 B0[4];
#pragma unroll
          for (int s = 0; s < 4; ++s)
            B0[s] = *(const half8*)&sm.rc.h[p][n * 136 + s * 32 + q * 8];
#pragma unroll
          for (int s = 0; s < 4; ++s)
#pragma unroll
            for (int tl = 0; tl < 4; ++tl)
              acc[tl] = __builtin_amdgcn_mfma_f32_16x16x32_f16(WA0[tl][s], B0[s], acc[tl], 0, 0, 0);

          {
            int tn = t + 4; if (tn > T_ - 1) tn = T_ - 1;
            const size_t so = (size_t)(tn & rmask) * 8192;
            pa[k] = xp[so];
            pb[k] = xp[so + 1];
          }

          float h0v[4];
          lstm_cell(acc, c0v, h0v);
          uint2 h0p;
          h0p.x = packh2f(h0v[0], h0v[1]);
          h0p.y = packh2f(h0v[2], h0v[3]);
          *(uint2*)&sm.rc.h[c][hoff] = h0p;
          hg[(size_t)t * 4096] = h0p;

          __syncthreads();  // drains vmcnt per-wave (h0g stores visible)
          if (k == 3 && tid == 0)
            __hip_atomic_store(&l0p[b16 * 16], t + 1, __ATOMIC_RELEASE,
                               __HIP_MEMORY_SCOPE_AGENT);
        }
      }
      if (tid == 0)
        __hip_atomic_store(&l0c[b16 * 16], g * 32 + 32, __ATOMIC_RELAXED,
                           __HIP_MEMORY_SCOPE_AGENT);
    }
  } else if (bid < 16) {
    // ---------------- Z1: z1(t) = b1 + Wih1 . h0(t) ----------------
    const int b16 = bid - 8;
    half8 WI[4][4];
#pragma unroll
    for (int tl = 0; tl < 4; ++tl)
#pragma unroll
      for (int s = 0; s < 4; ++s)
        WI[tl][s] = __builtin_bit_cast(half8, Wih1f[((w * 4 + tl) * 4 + s) * 64 + L]);
    f32x4 b1v[4];
#pragma unroll
    for (int tl = 0; tl < 4; ++tl) b1v[tl] = b1fD[(w * 64 + L) * 4 + tl];

    const int n2 = tid >> 5, jq = tid & 31;
    const uint2* hsrc = h0g + ((b16 * 16 + n2) * 32 + jq);
    uint4* zdst = z1f + (((size_t)b16 * 8 + w) * 64 + L) * 2;
    const int R2 = rmask2 + 1;
    uint2 hpf[4];

#pragma unroll 1
    for (int p0 = 0; p0 < T_; p0 += 4) {
      if (tid == 0) {
        while (__hip_atomic_load(&l0p[b16 * 16], __ATOMIC_ACQUIRE,
                                 __HIP_MEMORY_SCOPE_AGENT) < p0 + 4)
          __builtin_amdgcn_s_sleep(1);
        if (p0 + 4 > R2) {
          const int need = p0 + 12 - R2;  // z1-ring WAR margin
          while (__hip_atomic_load(&l1p[b16 * 16], __ATOMIC_RELAXED,
                                   __HIP_MEMORY_SCOPE_AGENT) < need)
            __builtin_amdgcn_s_sleep(8);
        }
      }
      __syncthreads();
#pragma unroll
      for (int k = 0; k < 4; ++k) hpf[k] = hsrc[(size_t)(p0 + k) * 4096];
#pragma unroll
      for (int k = 0; k < 4; ++k) {
        const int t = p0 + k;
        const int c = t & 1;
        *(uint2*)&sm.rc.h[c][n2 * 136 + jq * 4] = hpf[k];
        __syncthreads();
        half8 B[4];
#pragma unroll
        for (int s = 0; s < 4; ++s)
          B[s] = *(const half8*)&sm.rc.h[c][n * 136 + s * 32 + q * 8];
        f32x4 acc[4];
#pragma unroll
        for (int tl = 0; tl < 4; ++tl) acc[tl] = b1v[tl];
#pragma unroll
        for (int s = 0; s < 4; ++s)
#pragma unroll
          for (int tl = 0; tl < 4; ++tl)
            acc[tl] = __builtin_amdgcn_mfma_f32_16x16x32_f16(WI[tl][s], B[s], acc[tl], 0, 0, 0);
        uint4 o0, o1;
        o0.x = packh2f(acc[0][0], acc[0][1]); o0.y = packh2f(acc[0][2], acc[0][3]);
        o0.z = packh2f(acc[1][0], acc[1][1]); o0.w = packh2f(acc[1][2], acc[1][3]);
        o1.x = packh2f(acc[2][0], acc[2][1]); o1.y = packh2f(acc[2][2], acc[2][3]);
        o1.z = packh2f(acc[3][0], acc[3][1]); o1.w = packh2f(acc[3][2], acc[3][3]);
        const size_t zs = (size_t)(t & rmask2) * 8192;
        zdst[zs] = o0;
        zdst[zs + 1] = o1;
      }
      asm volatile("s_waitcnt vmcnt(0)" ::: "memory");
      __syncthreads();
      if (tid == 0)
        __hip_atomic_store(&z1p[b16 * 16], p0 + 4, __ATOMIC_RELEASE,
                           __HIP_MEMORY_SCOPE_AGENT);
    }
  } else if (bid < 24) {
    // ---------------- L1: layer-1 recurrence (Whh1 only) ----------------
    const int b16 = bid - 16;
    half8 WH[4][4];
#pragma unroll
    for (int tl = 0; tl < 4; ++tl)
#pragma unroll
      for (int s = 0; s < 4; ++s)
        WH[tl][s] = __builtin_bit_cast(half8, Whh1f[((w * 4 + tl) * 4 + s) * 64 + L]);

    f32x4 c1v = {0.f, 0.f, 0.f, 0.f};
    f32x4 pool = {0.f, 0.f, 0.f, 0.f};
    const int hoff = n * 136 + w * 16 + q * 4;
    *(uint2*)&sm.rc.h[1][hoff] = make_uint2(0u, 0u);
    __syncthreads();

    const uint4* zp = z1f + (((size_t)b16 * 8 + w) * 64 + L) * 2;
    uint4 pa[4], pb[4];

#pragma unroll 1
    for (int g4 = 0; g4 < 512; ++g4) {
      const int p0 = g4 * 4;
      if (tid == 0) {
        int tgt = p0 + 8; if (tgt > T_) tgt = T_;
        while (__hip_atomic_load(&z1p[b16 * 16], __ATOMIC_ACQUIRE,
                                 __HIP_MEMORY_SCOPE_AGENT) < tgt)
          __builtin_amdgcn_s_sleep(1);
      }
      __syncthreads();
      if (g4 == 0) {
#pragma unroll
        for (int k = 0; k < 4; ++k) {
          pa[k] = zp[(size_t)k * 8192];
          pb[k] = zp[(size_t)k * 8192 + 1];
        }
      }
#pragma unroll
      for (int k = 0; k < 4; ++k) {
        const int t = p0 + k;
        const int c = t & 1, p = c ^ 1;
        f32x4 acc[4];
        {
          half8 xlo = __builtin_bit_cast(half8, pa[k]);
          half8 xhi = __builtin_bit_cast(half8, pb[k]);
          acc[0] = (f32x4){(float)xlo[0], (float)xlo[1], (float)xlo[2], (float)xlo[3]};
          acc[1] = (f32x4){(float)xlo[4], (float)xlo[5], (float)xlo[6], (float)xlo[7]};
          acc[2] = (f32x4){(float)xhi[0], (float)xhi[1], (float)xhi[2], (float)xhi[3]};
          acc[3] = (f32x4){(float)xhi[4], (float)xhi[5], (float)xhi[6], (float)xhi[7]};
        }
        half8 B1[4];
#pragma unroll
        for (int s = 0; s < 4; ++s)
          B1[s] = *(const half8*)&sm.rc.h[p][n * 136 + s * 32 + q * 8];
#pragma unroll
        for (int s = 0; s < 4; ++s)
#pragma unroll
          for (int tl = 0; tl < 4; ++tl)
            acc[tl] = __builtin_amdgcn_mfma_f32_16x16x32_f16(WH[tl][s], B1[s], acc[tl], 0, 0, 0);

        {
          int tn = t + 4; if (tn > T_ - 1) tn = T_ - 1;
          const size_t so = (size_t)(tn & rmask2) * 8192;
          pa[k] = zp[so];
          pb[k] = zp[so + 1];
        }

        float h1v[4];
        lstm_cell(acc, c1v, h1v);
        pool[0] += h1v[0]; pool[1] += h1v[1];
        pool[2] += h1v[2]; pool[3] += h1v[3];
        uint2 h1p;
        h1p.x = packh2f(h1v[0], h1v[1]);
        h1p.y = packh2f(h1v[2], h1v[3]);
        *(uint2*)&sm.rc.h[c][hoff] = h1p;
        __syncthreads();
      }
      if ((g4 & 1) && tid == 0)
        __hip_atomic_store(&l1p[b16 * 16], p0 + 4, __ATOMIC_RELEASE,
                           __HIP_MEMORY_SCOPE_AGENT);
    }
    psave[(b16 * 8 + w) * 64 + L] = pool;
  } else {
    // ---------------- conv + x0 projection workers ----------------
    const int wi = bid - 24;
    const int co = tid & 127;
    float cw[48];
#pragma unroll
    for (int i = 0; i < 12; ++i) {
      const float4 v = *(const float4*)(conv_w + co * 48 + i * 4);
      cw[i * 4 + 0] = v.x; cw[i * 4 + 1] = v.y;
      cw[i * 4 + 2] = v.z; cw[i * 4 + 3] = v.w;
    }
    const float cb = conv_b[co];
    half8 WB[4][4];
#pragma unroll
    for (int nt4 = 0; nt4 < 4; ++nt4)
#pragma unroll
      for (int s = 0; s < 4; ++s)
        WB[nt4][s] = __builtin_bit_cast(half8, WB0f[((w * 4 + nt4) * 4 + s) * 64 + L]);
    float b0v[4];
#pragma unroll
    for (int nt4 = 0; nt4 < 4; ++nt4) {
      int gg = (w * 4 + nt4) * 16 + n;
      b0v[nt4] = (b_ih0[gg] + b_hh0[gg]) * (((gg >> 7) == 2) ? L2E2 : L2E);
    }
    const int R = rmask + 1;

    for (int u = wi; u < 8192; u += WCV) {
      const int tile = u >> 7, b = u & 127;
      const int t0c = tile * 32;
      if (t0c + 40 > R) {
        const int need = t0c + 40 - R;
        if (tid == 0)
          while (__hip_atomic_load(&l0c[(b >> 4) * 16], __ATOMIC_RELAXED,
                                   __HIP_MEMORY_SCOPE_AGENT) < need)
            __builtin_amdgcn_s_sleep(8);
      }
      __syncthreads();

      for (int idx = tid; idx < 544; idx += 512) {
        int row = idx >> 4, cc2 = idx & 15;
        int gt = t0c - 1 + row;
        sm.wk.xs[idx] = (gt >= 0 && gt < T_) ? x[((size_t)b * T_ + gt) * C_ + cc2] : 0.f;
      }
      __syncthreads();

#pragma unroll
      for (int pp = 0; pp < 8; ++pp) {
        int r = pp * 4 + (tid >> 7);
        float acc = cb;
#pragma unroll
        for (int c16 = 0; c16 < 16; ++c16)
#pragma unroll
          for (int kk = 0; kk < 3; ++kk)
            acc += sm.wk.xs[(r + kk) * 16 + c16] * cw[c16 * 3 + kk];
        acc = acc >= 0.f ? acc : 0.01f * acc;
        sm.wk.yh[r * 136 + co] = (_Float16)acc;
      }
      __syncthreads();

#pragma unroll
      for (int mt = 0; mt < 2; ++mt) {
        half8 A[4];
#pragma unroll
        for (int s = 0; s < 4; ++s)
          A[s] = *(const half8*)&sm.wk.yh[(mt * 16 + n) * 136 + s * 32 + q * 8];
#pragma unroll
        for (int nt4 = 0; nt4 < 4; ++nt4) {
          f32x4 acc = {b0v[nt4], b0v[nt4], b0v[nt4], b0v[nt4]};
#pragma unroll
          for (int s = 0; s < 4; ++s)
            acc = __builtin_amdgcn_mfma_f32_16x16x32_f16(A[s], WB[nt4][s], acc, 0, 0, 0);
          int tau = w * 4 + nt4;
          int off = (tau & 7) * 64 + (n >> 2) * 16 + (tau >> 3) * 4 + (n & 3);
#pragma unroll
          for (int reg = 0; reg < 4; ++reg)
            sm.wk.x0S[(mt * 16 + q * 4 + reg) * 512 + off] = (_Float16)acc[reg];
        }
      }
      __syncthreads();

      const int bn = b & 15, bb16 = b >> 4;
      const int trb = t0c & rmask;
#pragma unroll
      for (int kk = 0; kk < 2; ++kk) {
        int cc = kk * 512 + tid;
        int r = cc >> 5, wq = cc & 31;
        int w2 = wq >> 2, q2 = wq & 3;
        const uint4* src = (const uint4*)&sm.wk.x0S[r * 512 + wq * 16];
        size_t gidx = ((((size_t)(trb + r) * 8 + bb16) * 8 + w2) * 64 + (bn + 16 * q2)) * 2;
        x0f[gidx] = src[0];
        x0f[gidx + 1] = src[1];
      }
      asm volatile("s_waitcnt vmcnt(0)" ::: "memory");
      __syncthreads();
      if (tid == 0)
        __hip_atomic_fetch_add(&xready[tile * 8 + bb16], 1, __ATOMIC_RELEASE,
                               __HIP_MEMORY_SCOPE_AGENT);
    }
  }
}

// ---------------------------------------------------------------------------
__global__ __launch_bounds__(128) void final_kernel(
    const f32x4* __restrict__ psave, const float* __restrict__ lin_w,
    const float* __restrict__ lin_b, float* __restrict__ out) {
  int b = threadIdx.x;
  int n = b & 15, b16 = b >> 4;
  float acc = 0.f;
  for (int w = 0; w < 8; ++w)
#pragma unroll
    for (int q = 0; q < 4; ++q) {
      f32x4 v = psave[(b16 * 8 + w) * 64 + n + 16 * q];
#pragma unroll
      for (int reg = 0; reg < 4; ++reg)
        acc += v[reg] * lin_w[w * 16 + q * 4 + reg];
    }
  out[b] = acc * (1.0f / (float)T_) + lin_b[0];
}

// ---------------------------------------------------------------------------
extern "C" void kernel_launch(void* const* d_in, const int* in_sizes, int n_in,
                              void* d_out, int out_size, void* d_ws, size_t ws_size,
                              hipStream_t stream) {
  (void)in_sizes; (void)n_in; (void)out_size;
  const float* x      = (const float*)d_in[0];
  const float* conv_w = (const float*)d_in[1];
  const float* conv_b = (const float*)d_in[2];
  const float* w_ih0  = (const float*)d_in[3];
  const float* w_hh0  = (const float*)d_in[4];
  const float* b_ih0  = (const float*)d_in[5];
  const float* b_hh0  = (const float*)d_in[6];
  const float* w_ih1  = (const float*)d_in[7];
  const float* w_hh1  = (const float*)d_in[8];
  const float* b_ih1  = (const float*)d_in[9];
  const float* b_hh1  = (const float*)d_in[10];
  const float* lin_w  = (const float*)d_in[11];
  const float* lin_b  = (const float*)d_in[12];

  char* ws = (char*)d_ws;
  uint4* Wf0   = (uint4*)(ws + 0);        // 131072
  uint4* Wih1f = (uint4*)(ws + 131072);   // 131072
  uint4* Whh1f = (uint4*)(ws + 262144);   // 131072
  uint4* WB0f  = (uint4*)(ws + 393216);   // 131072
  f32x4* b1fD  = (f32x4*)(ws + 524288);   // 32768
  f32x4* psave = (f32x4*)(ws + 557056);   // 65536
  int*   flags = (int*)(ws + 622592);     // 4096 (1024 ints, line-padded)
  uint2* h0g   = (uint2*)(ws + 626688);   // 67108864 (full-T h0 stream)
  const size_t base = 626688 + 67108864;  // 67735552

  int R = 256, R2 = 256;  // x0 ring, z1 ring (steps)
  while (R > 64 && base + ((size_t)R + (size_t)R2) * 131072 > ws_size) {
    R >>= 1; R2 >>= 1;
  }
  uint4* x0f = (uint4*)(ws + base);
  uint4* z1f = (uint4*)(ws + base + (size_t)R * 131072);

  hipMemsetAsync(flags, 0, 4096, stream);
  pack_kernel<<<136, 256, 0, stream>>>(w_ih0, w_hh0, w_ih1, w_hh1, b_ih1, b_hh1,
                                       Wf0, Wih1f, Whh1f, WB0f, b1fD);
  persist_kernel<<<NBLK, 512, 0, stream>>>(
      x, conv_w, conv_b, b_ih0, b_hh0, Wf0, Wih1f, Whh1f, WB0f, b1fD,
      x0f, h0g, z1f, psave, flags, R - 1, R2 - 1);
  final_kernel<<<1, 128, 0, stream>>>(psave, lin_w, lin_b, (float*)d_out);
}